// Round 6
// baseline (182.719 us; speedup 1.0000x reference)
//
#include <hip/hip_runtime.h>
#include <math.h>
#include <limits.h>

#define NQ     64
#define NE     10000
#define D      256
#define K      10
#define NBLK   500         // blocks in kernel 1 == partial lists per query
#define EPB    20          // entities per block (500*20 = 10000)
#define EPS    10          // entities per slot (sequential per wave)
#define TPB    512
#define SLOT   11          // padded merge-slot stride (entries)
#define SCALE  8388608.0f  // 2^23: inputs are multiples of 2^-23 in [0,1) -> exact u32

// LDS layout (44032 B dynamic):
//   [0, 35328)        Q stage chunk: 32 rows x 69 uint4 slots x 16B (padded; f32 staged)
//   [35328, 44032)    ebuf: 8 waves x 1088 B (4 quarters x 272 B, 16B pad per quarter)
//   merge overlay:    Mv double[128*SLOT] @0 (11264), Mi int[128*SLOT] @11264 (5632)
#define QSTG_BYTES 35328
#define EB_BASE    QSTG_BYTES
#define EB_STRIDE  1088
#define LDS_BYTES  (EB_BASE + 8 * EB_STRIDE)   // 44032

// ---------- comparators (match lax.top_k: ties -> lower index first) ----------
__device__ __forceinline__ bool better_top(double v, int i, double v2, int i2) {
    return (v > v2) || (v == v2 && i < i2);
}
__device__ __forceinline__ bool better_bot(double v, int i, double v2, int i2) {
    return (v < v2) || (v == v2 && i < i2);
}

// merge two sorted K-lists in LDS (slot indices A, B; stride SLOT) -> into A
template <bool TOP>
__device__ __forceinline__ void merge_slots(double* Mv, int* Mi, int A, int B) {
    double ov[K]; int oi[K];
    int a = 0, b = 0;
#pragma unroll
    for (int o = 0; o < K; ++o) {
        double va = Mv[A * SLOT + a]; int ia = Mi[A * SLOT + a];
        double vb = Mv[B * SLOT + b]; int ib = Mi[B * SLOT + b];
        bool pick = TOP ? better_top(va, ia, vb, ib) : better_bot(va, ia, vb, ib);
        ov[o] = pick ? va : vb;
        oi[o] = pick ? ia : ib;
        if (pick) ++a; else ++b;
    }
#pragma unroll
    for (int o = 0; o < K; ++o) { Mv[A * SLOT + o] = ov[o]; Mi[A * SLOT + o] = oi[o]; }
}

// ---------------- kernel 0: exact u32 entity row sums (wave per row) ----------------
__global__ __launch_bounds__(256) void ent_sums(const float* __restrict__ E,
                                                unsigned* __restrict__ Se) {
    const int w = threadIdx.x >> 6, l = threadIdx.x & 63;
    const int j = blockIdx.x * 4 + w;          // 2500 blocks * 4 waves = 10000 rows
    float4 v = reinterpret_cast<const float4*>(E)[(size_t)j * 64 + l];
    unsigned s = (unsigned)(v.x * SCALE) + (unsigned)(v.y * SCALE)
               + (unsigned)(v.z * SCALE) + (unsigned)(v.w * SCALE);
#pragma unroll
    for (int m = 1; m < 64; m <<= 1) s += (unsigned)__shfl_xor((int)s, m, 64);
    if (l == 0) Se[j] = s;
}

// ---------------- kernel 1: register-Q quarters ----------------
// wave w: group g=w&3 (queries 16g..16g+15), slot s=w>>2 (entities jb+2k+s)
// lane l: query q = 16g + (l>>2); sub = l&3 owns dim quarter [64*sub, 64*sub+64)
__global__ __launch_bounds__(TPB, 2) void jac_part(
        const float* __restrict__ Q, const float* __restrict__ E,
        const unsigned* __restrict__ Se,
        double* __restrict__ pvT, double* __restrict__ pvB,
        int* __restrict__ piT, int* __restrict__ piB) {
    extern __shared__ char smem[];
    float4* Qst = (float4*)smem;

    const int t   = threadIdx.x;
    const int l   = t & 63;
    const int w   = t >> 6;
    const int g   = w & 3;
    const int s   = w >> 2;
    const int qi  = l >> 2;
    const int sub = l & 3;
    const int q   = 16 * g + qi;
    const int b   = blockIdx.x;

    const float4* Q4 = (const float4*)Q;
    uint4 qreg[16];
    unsigned Sq = 0;

    // ---- stage chunk 0 (queries 0..31, f32, padded layout) ----
#pragma unroll
    for (int r = 0; r < 4; ++r) {
        const int e = t + 512 * r;              // coalesced
        float4 v = Q4[e];
        const int row = e >> 6, col = e & 63;
        Qst[row * 69 + (col >> 4) * 17 + (col & 15)] = v;
    }
    __syncthreads();
    if (g < 2) {
        const int rrow = 16 * (g & 1) + qi;
        unsigned acc = 0;
#pragma unroll
        for (int gg = 0; gg < 16; ++gg) {
            float4 v = Qst[rrow * 69 + sub * 17 + gg];
            uint4 u;
            u.x = (unsigned)(v.x * SCALE); u.y = (unsigned)(v.y * SCALE);
            u.z = (unsigned)(v.z * SCALE); u.w = (unsigned)(v.w * SCALE);
            qreg[gg] = u;
            acc += u.x + u.y + u.z + u.w;
        }
        Sq = acc;
    }
    __syncthreads();
    // ---- stage chunk 1 (queries 32..63) ----
#pragma unroll
    for (int r = 0; r < 4; ++r) {
        const int e = t + 512 * r;
        float4 v = Q4[2048 + e];
        const int row = e >> 6, col = e & 63;
        Qst[row * 69 + (col >> 4) * 17 + (col & 15)] = v;
    }
    __syncthreads();
    if (g >= 2) {
        const int rrow = 16 * (g & 1) + qi;
        unsigned acc = 0;
#pragma unroll
        for (int gg = 0; gg < 16; ++gg) {
            float4 v = Qst[rrow * 69 + sub * 17 + gg];
            uint4 u;
            u.x = (unsigned)(v.x * SCALE); u.y = (unsigned)(v.y * SCALE);
            u.z = (unsigned)(v.z * SCALE); u.w = (unsigned)(v.w * SCALE);
            qreg[gg] = u;
            acc += u.x + u.y + u.z + u.w;
        }
        Sq = acc;
    }
    // full-row query sum: combine quarter sums (exact int butterfly over sub lanes)
    Sq += (unsigned)__shfl_xor((int)Sq, 1, 64);
    Sq += (unsigned)__shfl_xor((int)Sq, 2, 64);

    // ---- main loop: slot streams entities, all LDS ops wave-private ----
    char* ebbase = smem + EB_BASE + w * EB_STRIDE;
    const int ebw_off = ((l >> 4) * 272) + ((l & 15) * 16);  // quarter (l>>4), elem (l&15)
    const int ebr_off = sub * 272;

    unsigned recI[EPS], recU[EPS];
    const int jbase = b * EPB + s;             // entity j = jbase + 2k
    const float4* E4 = (const float4*)E;

    float4 er = E4[(size_t)jbase * 64 + l];    // coalesced full row
    unsigned se = Se[jbase];

#pragma unroll
    for (int k = 0; k < EPS; ++k) {
        const int kn = (k + 1 < EPS) ? k + 1 : k;      // clamp: harmless re-read last iter
        const int jn = jbase + 2 * kn;
        float4 ern = E4[(size_t)jn * 64 + l];          // prefetch next row
        unsigned sen = Se[jn];

        uint4 eu;
        eu.x = (unsigned)(er.x * SCALE); eu.y = (unsigned)(er.y * SCALE);
        eu.z = (unsigned)(er.z * SCALE); eu.w = (unsigned)(er.w * SCALE);
        *(uint4*)(ebbase + ebw_off) = eu;              // wave-private; DS in-order intra-wave

        unsigned a0 = 0, a1 = 0;
#pragma unroll
        for (int gg = 0; gg < 16; ++gg) {
            uint4 ev = *(const uint4*)(ebbase + ebr_off + gg * 16);  // 4-addr bcast, pad->no conflict
            uint4 qv = qreg[gg];
            a0 += min(qv.x, ev.x) + min(qv.y, ev.y);
            a1 += min(qv.z, ev.z) + min(qv.w, ev.w);
        }
        unsigned ih = a0 + a1;
        ih += (unsigned)__shfl_xor((int)ih, 1, 64);    // combine quarters (exact int)
        ih += (unsigned)__shfl_xor((int)ih, 2, 64);
        recI[k] = ih;
        recU[k] = Sq + se - ih;                        // min+max == q+e exactly; < 2^32
        er = ern; se = sen;
    }

    // ---- deferred selection: 10 candidates, registers only ----
    double tv[K]; int ti[K]; double bv[K]; int bi[K];
#pragma unroll
    for (int o = 0; o < K; ++o) {
        tv[o] = -INFINITY; ti[o] = INT_MAX;
        bv[o] =  INFINITY; bi[o] = INT_MAX;
    }
#pragma unroll
    for (int k = 0; k < EPS; ++k) {
        const int j = jbase + 2 * k;
        // scaled by 2^23 in num and den -> IEEE quotient identical to unscaled
        double jac = (double)recI[k] / (double)recU[k];

        if (better_top(jac, j, tv[K - 1], ti[K - 1])) {
            tv[K - 1] = jac; ti[K - 1] = j;
#pragma unroll
            for (int ss = K - 1; ss > 0; --ss) {
                if (better_top(tv[ss], ti[ss], tv[ss - 1], ti[ss - 1])) {
                    double tm = tv[ss]; tv[ss] = tv[ss - 1]; tv[ss - 1] = tm;
                    int    ii = ti[ss]; ti[ss] = ti[ss - 1]; ti[ss - 1] = ii;
                }
            }
        }
        if (better_bot(jac, j, bv[K - 1], bi[K - 1])) {
            bv[K - 1] = jac; bi[K - 1] = j;
#pragma unroll
            for (int ss = K - 1; ss > 0; --ss) {
                if (better_bot(bv[ss], bi[ss], bv[ss - 1], bi[ss - 1])) {
                    double tm = bv[ss]; bv[ss] = bv[ss - 1]; bv[ss - 1] = tm;
                    int    ii = bi[ss]; bi[ss] = bi[ss - 1]; bi[ss - 1] = ii;
                }
            }
        }
    }

    // ---- in-block merge: 2 slot-lists per query -> 1 list/query/block ----
    __syncthreads();
    double* Mv = (double*)smem;                   // 128*SLOT*8 = 11264
    int*    Mi = (int*)(smem + 128 * SLOT * 8);   // 128*SLOT*4 =  5632
    const bool sub0 = (sub == 0);
    const int  slot = q * 2 + s;

    // TOP
    if (sub0) {
#pragma unroll
        for (int o = 0; o < K; ++o) { Mv[slot * SLOT + o] = tv[o]; Mi[slot * SLOT + o] = ti[o]; }
    }
    __syncthreads();
    if (t < NQ) {
        merge_slots<true>(Mv, Mi, 2 * t, 2 * t + 1);
        const size_t off = ((size_t)b * NQ + t) * K;
#pragma unroll
        for (int o = 0; o < K; ++o) { pvT[off + o] = Mv[2 * t * SLOT + o]; piT[off + o] = Mi[2 * t * SLOT + o]; }
    }
    __syncthreads();
    // BOT
    if (sub0) {
#pragma unroll
        for (int o = 0; o < K; ++o) { Mv[slot * SLOT + o] = bv[o]; Mi[slot * SLOT + o] = bi[o]; }
    }
    __syncthreads();
    if (t < NQ) {
        merge_slots<false>(Mv, Mi, 2 * t, 2 * t + 1);
        const size_t off = ((size_t)b * NQ + t) * K;
#pragma unroll
        for (int o = 0; o < K; ++o) { pvB[off + o] = Mv[2 * t * SLOT + o]; piB[off + o] = Mi[2 * t * SLOT + o]; }
    }
}

// ---------------- kernel 2: merge 500 block lists per query ----------------
template <bool TOP>
__device__ __forceinline__ void merge_query(const double* __restrict__ V,
                                            const int* __restrict__ I,
                                            int q, double* Mv, int* Mi,
                                            int* __restrict__ outp) {
    const int t = threadIdx.x;
    double ov[K]; int oi[K];
    const int lb = t + 256;
    const size_t sa = ((size_t)t * NQ + q) * K;
    if (lb < NBLK) {
        const size_t sb = ((size_t)lb * NQ + q) * K;
        int a = 0, bn = 0;
#pragma unroll
        for (int o = 0; o < K; ++o) {
            double va = V[sa + a];  int ia = I[sa + a];
            double vb = V[sb + bn]; int ib = I[sb + bn];
            bool pick = TOP ? better_top(va, ia, vb, ib) : better_bot(va, ia, vb, ib);
            ov[o] = pick ? va : vb;
            oi[o] = pick ? ia : ib;
            if (pick) ++a; else ++bn;
        }
    } else {
#pragma unroll
        for (int o = 0; o < K; ++o) { ov[o] = V[sa + o]; oi[o] = I[sa + o]; }
    }
#pragma unroll
    for (int o = 0; o < K; ++o) { Mv[t * SLOT + o] = ov[o]; Mi[t * SLOT + o] = oi[o]; }
    __syncthreads();
    for (int ss = 128; ss >= 1; ss >>= 1) {
        if (t < ss) merge_slots<TOP>(Mv, Mi, t, t + ss);
        __syncthreads();
    }
    if (t == 0) {
#pragma unroll
        for (int o = 0; o < K; ++o) outp[o] = Mi[o];
    }
    __syncthreads();
}

__global__ __launch_bounds__(256) void final_merge(
        const double* __restrict__ pvT, const double* __restrict__ pvB,
        const int* __restrict__ piT, const int* __restrict__ piB,
        int* __restrict__ out) {
    __shared__ double Mv[256 * SLOT];   // 22528 B
    __shared__ int    Mi[256 * SLOT];   // 11264 B
    const int q = blockIdx.x;
    merge_query<true >(pvT, piT, q, Mv, Mi, out + q * K);
    merge_query<false>(pvB, piB, q, Mv, Mi, out + NQ * K + q * K);
}

extern "C" void kernel_launch(void* const* d_in, const int* in_sizes, int n_in,
                              void* d_out, int out_size, void* d_ws, size_t ws_size,
                              hipStream_t stream) {
    const float* Q = (const float*)d_in[0];   // [64, 256]
    const float* E = (const float*)d_in[1];   // [10000, 256]
    int* out = (int*)d_out;                   // 640 top idx + 640 bot idx

    // workspace: Se(u32) + block-major partial lists (7.72 MB)
    char* ws = (char*)d_ws;
    unsigned* Se  = (unsigned*)(ws);          // 40,960 (padded)
    double*   pvT = (double*)(ws + 40960);    // 500*64*10*8 = 2,560,000
    double*   pvB = (double*)(ws + 2600960);  // 2,560,000
    int*      piT = (int*)   (ws + 5160960);  // 1,280,000
    int*      piB = (int*)   (ws + 6440960);  // 1,280,000

    hipLaunchKernelGGL(ent_sums, dim3(NE / 4), dim3(256), 0, stream, E, Se);
    hipLaunchKernelGGL(jac_part, dim3(NBLK), dim3(TPB), LDS_BYTES, stream,
                       Q, E, Se, pvT, pvB, piT, piB);
    hipLaunchKernelGGL(final_merge, dim3(NQ), dim3(256), 0, stream,
                       pvT, pvB, piT, piB, out);
}

// Round 7
// 109.729 us; speedup vs baseline: 1.6652x; 1.6652x over previous
//
#include <hip/hip_runtime.h>
#include <math.h>
#include <limits.h>

#define NQ     64
#define NE     10000
#define D      256
#define G4T    64          // float4 groups per full row
#define GH     32          // groups per sublane (half row)
#define K      10
#define NSTRIP 500
#define EPB    20          // entities per strip (500*20 = 10000)
#define TPB    512
#define NWAVE  8
#define MAXEPW 3           // w<4: 3 entities, w>=4: 2
#define SLOT   11          // padded merge-slot stride (entries)
#define QTBYTES   32768
#define EBSTRIDE  1040     // 1024 + 16B pad between sublane halves (bank-alias fix)
#define LDSBYTES  (QTBYTES + NWAVE * EBSTRIDE)   // 41088

#define SCALE 8388608.0f   // 2^23: inputs are multiples of 2^-23 in [0,1) -> exact u32

// ---------- comparators (match lax.top_k: ties -> lower index first) ----------
__device__ __forceinline__ bool better_top(double v, int i, double v2, int i2) {
    return (v > v2) || (v == v2 && i < i2);
}
__device__ __forceinline__ bool better_bot(double v, int i, double v2, int i2) {
    return (v < v2) || (v == v2 && i < i2);
}

// merge two sorted K-lists in LDS (slot indices A, B; stride SLOT) -> into A
template <bool TOP>
__device__ __forceinline__ void merge_slots(double* Mv, int* Mi, int A, int B) {
    double ov[K]; int oi[K];
    int a = 0, b = 0;
#pragma unroll
    for (int o = 0; o < K; ++o) {
        double va = Mv[A * SLOT + a]; int ia = Mi[A * SLOT + a];
        double vb = Mv[B * SLOT + b]; int ib = Mi[B * SLOT + b];
        bool pick = TOP ? better_top(va, ia, vb, ib) : better_bot(va, ia, vb, ib);
        ov[o] = pick ? va : vb;
        oi[o] = pick ? ia : ib;
        if (pick) ++a; else ++b;
    }
#pragma unroll
    for (int o = 0; o < K; ++o) { Mv[A * SLOT + o] = ov[o]; Mi[A * SLOT + o] = oi[o]; }
}

// ---------------- kernel 0: exact u32 entity row sums (wave per row) ----------------
__global__ __launch_bounds__(256) void ent_sums(const float* __restrict__ E,
                                                unsigned* __restrict__ Se) {
    const int w = threadIdx.x >> 6, l = threadIdx.x & 63;
    const int j = blockIdx.x * 4 + w;          // 2500 blocks * 4 waves = 10000 rows
    float4 v = reinterpret_cast<const float4*>(E)[(size_t)j * G4T + l];
    unsigned s = (unsigned)(v.x * SCALE) + (unsigned)(v.y * SCALE)
               + (unsigned)(v.z * SCALE) + (unsigned)(v.w * SCALE);
#pragma unroll
    for (int m = 1; m < 64; m <<= 1) s += (unsigned)__shfl_xor((int)s, m, 64);
    if (l == 0) Se[j] = s;
}

// ---------------- kernel 1 ----------------
// grid = 1000: strip = bid>>1 (500 strips x 20 entities), h = bid&1 (query half)
// lane l: query q = qbase + (l>>1), sublane sub = l&1 owns groups [sub*32, sub*32+32)
// LDS (41088 B dynamic):
//   [0, 32768)        QT uint4[32][64] (pre-scaled integer query values)
//   [32768, 41088)    ebuf 8 x 1040B (wave-private, 16B pad between halves);
//                     transiently SqP unsigned[512]
//   merge overlay:    Mv double[256*SLOT] @0 (22528), Mi int[256*SLOT] @22528 (11264)
__global__ __launch_bounds__(TPB, 3) void jac_part(
        const float* __restrict__ Q, const float* __restrict__ E,
        const unsigned* __restrict__ Se,
        double* __restrict__ pvT, double* __restrict__ pvB,
        int* __restrict__ piT, int* __restrict__ piB) {
    extern __shared__ char smem[];
    uint4* QT = (uint4*)smem;

    const int t   = threadIdx.x;
    const int l   = t & 63;
    const int w   = t >> 6;
    const int q   = l >> 1;
    const int sub = l & 1;
    const int strip = blockIdx.x >> 1;
    const int qbase = (blockIdx.x & 1) * 32;

    // ---- stage QT (integer) + per-thread Sq partials ----
    unsigned* SqP = (unsigned*)(smem + QTBYTES);
    {
        const int sq = t >> 4, c = t & 15;
        unsigned acc = 0;
#pragma unroll
        for (int r = 0; r < 4; ++r) {
            const int gg = c + 16 * r;
            float4 v = reinterpret_cast<const float4*>(Q)[(qbase + sq) * G4T + gg];
            uint4 u;
            u.x = (unsigned)(v.x * SCALE); u.y = (unsigned)(v.y * SCALE);
            u.z = (unsigned)(v.z * SCALE); u.w = (unsigned)(v.w * SCALE);
            QT[(gg & 31) * 64 + (2 * sq + (gg >> 5))] = u;
            acc += u.x + u.y + u.z + u.w;
        }
        SqP[t] = acc;
    }
    __syncthreads();
    unsigned Sq = 0;
#pragma unroll
    for (int p = 0; p < 16; ++p) Sq += SqP[q * 16 + ((p + q) & 15)];  // rotated: 2-way only
    __syncthreads();   // SqP region becomes ebuf

    char* ebbase = smem + QTBYTES + w * EBSTRIDE;
    // write: lane l -> byte l*16 (+16 pad if upper half); read: sublane half base
    uint4* ebw = (uint4*)(ebbase + ((l >> 5) << 4));
    const uint4* ebr = (const uint4*)(ebbase + sub * 528);

    const int jb = strip * EPB;
    unsigned recI[MAXEPW], recU[MAXEPW];
    const int ncand = (EPB - 1 - w) / NWAVE + 1;   // wave-uniform: w<4 -> 3, else 2

    // prologue: first row + its precomputed sum
    float4 er = reinterpret_cast<const float4*>(E)[(size_t)(jb + w) * G4T + l];
    unsigned se = Se[jb + w];

#pragma unroll
    for (int s = 0; s < MAXEPW; ++s) {
        const int i = w + NWAVE * s;
        if (i >= EPB) break;                           // wave-uniform exit
        const int i2 = (i + NWAVE < EPB) ? i + NWAVE : i;   // clamp: harmless re-read
        // prefetch next row + sum (latency hides under g-loop)
        float4 ern = reinterpret_cast<const float4*>(E)[(size_t)(jb + i2) * G4T + l];
        unsigned sen = Se[jb + i2];

        uint4 eu;
        eu.x = (unsigned)(er.x * SCALE); eu.y = (unsigned)(er.y * SCALE);
        eu.z = (unsigned)(er.z * SCALE); eu.w = (unsigned)(er.w * SCALE);
        ebw[l] = eu;   // wave-private stage; DS ops are in-order intra-wave

        unsigned a0 = 0, a1 = 0;
#pragma unroll 8
        for (int g = 0; g < GH; ++g) {
            uint4 qv = QT[g * 64 + l];    // contiguous 1KB per wave: conflict-free
            uint4 ev = ebr[g];            // 2-address broadcast, banks differ (pad): free
            a0 += min(qv.x, ev.x) + min(qv.y, ev.y);
            a1 += min(qv.z, ev.z) + min(qv.w, ev.w);
        }
        unsigned ih = a0 + a1;
        unsigned inter = ih + (unsigned)__shfl_xor((int)ih, 1, 64);  // combine sublanes (exact)
        recI[s] = inter;
        recU[s] = Sq + se - inter;        // min+max == q+e exactly; < 2^32
        er = ern; se = sen;
    }

    // ---- deferred selection: <=3 candidates, registers only ----
    double tv[K]; int ti[K]; double bv[K]; int bi[K];
#pragma unroll
    for (int o = 0; o < K; ++o) {
        tv[o] = -INFINITY; ti[o] = INT_MAX;
        bv[o] =  INFINITY; bi[o] = INT_MAX;
    }
#pragma unroll
    for (int s = 0; s < MAXEPW; ++s) {
        if (s >= ncand) break;                         // wave-uniform
        const int j = jb + w + NWAVE * s;
        // scaled by 2^23 in num and den -> IEEE quotient identical to unscaled
        double jac = (double)recI[s] / (double)recU[s];

        if (better_top(jac, j, tv[K - 1], ti[K - 1])) {
            tv[K - 1] = jac; ti[K - 1] = j;
#pragma unroll
            for (int ss = K - 1; ss > 0; --ss) {
                if (better_top(tv[ss], ti[ss], tv[ss - 1], ti[ss - 1])) {
                    double tm = tv[ss]; tv[ss] = tv[ss - 1]; tv[ss - 1] = tm;
                    int    ii = ti[ss]; ti[ss] = ti[ss - 1]; ti[ss - 1] = ii;
                }
            }
        }
        if (better_bot(jac, j, bv[K - 1], bi[K - 1])) {
            bv[K - 1] = jac; bi[K - 1] = j;
#pragma unroll
            for (int ss = K - 1; ss > 0; --ss) {
                if (better_bot(bv[ss], bi[ss], bv[ss - 1], bi[ss - 1])) {
                    double tm = bv[ss]; bv[ss] = bv[ss - 1]; bv[ss - 1] = tm;
                    int    ii = bi[ss]; bi[ss] = bi[ss - 1]; bi[ss - 1] = ii;
                }
            }
        }
    }

    // ---- in-block merge across 8 waves, even lanes only (sublanes identical) ----
    __syncthreads();
    double* Mv = (double*)smem;
    int*    Mi = (int*)(smem + 256 * SLOT * 8);

    // TOP pass
    if (sub == 0) {
        const int slot = w * 32 + q;
#pragma unroll
        for (int o = 0; o < K; ++o) { Mv[slot * SLOT + o] = tv[o]; Mi[slot * SLOT + o] = ti[o]; }
    }
    __syncthreads();
    for (int s = 4; s >= 1; s >>= 1) {
        if (sub == 0 && w < s) merge_slots<true>(Mv, Mi, w * 32 + q, (w + s) * 32 + q);
        __syncthreads();
    }
    if (sub == 0 && w == 0) {
        const size_t slot = ((size_t)strip * NQ + qbase + q) * K;
#pragma unroll
        for (int o = 0; o < K; ++o) { pvT[slot + o] = Mv[q * SLOT + o]; piT[slot + o] = Mi[q * SLOT + o]; }
    }
    __syncthreads();

    // BOT pass
    if (sub == 0) {
        const int slot = w * 32 + q;
#pragma unroll
        for (int o = 0; o < K; ++o) { Mv[slot * SLOT + o] = bv[o]; Mi[slot * SLOT + o] = bi[o]; }
    }
    __syncthreads();
    for (int s = 4; s >= 1; s >>= 1) {
        if (sub == 0 && w < s) merge_slots<false>(Mv, Mi, w * 32 + q, (w + s) * 32 + q);
        __syncthreads();
    }
    if (sub == 0 && w == 0) {
        const size_t slot = ((size_t)strip * NQ + qbase + q) * K;
#pragma unroll
        for (int o = 0; o < K; ++o) { pvB[slot + o] = Mv[q * SLOT + o]; piB[slot + o] = Mi[q * SLOT + o]; }
    }
}

// ---------------- kernel 2: merge 500 strip lists per query ----------------
template <bool TOP>
__device__ __forceinline__ void merge_query(const double* __restrict__ V,
                                            const int* __restrict__ I,
                                            int q, double* Mv, int* Mi,
                                            int* __restrict__ outp) {
    const int t = threadIdx.x;
    double ov[K]; int oi[K];
    const int lb = t + 256;
    const size_t sa = ((size_t)t * NQ + q) * K;
    if (lb < NSTRIP) {
        const size_t sb = ((size_t)lb * NQ + q) * K;
        int a = 0, bn = 0;
#pragma unroll
        for (int o = 0; o < K; ++o) {
            double va = V[sa + a];  int ia = I[sa + a];
            double vb = V[sb + bn]; int ib = I[sb + bn];
            bool pick = TOP ? better_top(va, ia, vb, ib) : better_bot(va, ia, vb, ib);
            ov[o] = pick ? va : vb;
            oi[o] = pick ? ia : ib;
            if (pick) ++a; else ++bn;
        }
    } else {
#pragma unroll
        for (int o = 0; o < K; ++o) { ov[o] = V[sa + o]; oi[o] = I[sa + o]; }
    }
#pragma unroll
    for (int o = 0; o < K; ++o) { Mv[t * SLOT + o] = ov[o]; Mi[t * SLOT + o] = oi[o]; }
    __syncthreads();
    for (int ss = 128; ss >= 1; ss >>= 1) {
        if (t < ss) merge_slots<TOP>(Mv, Mi, t, t + ss);
        __syncthreads();
    }
    if (t == 0) {
#pragma unroll
        for (int o = 0; o < K; ++o) outp[o] = Mi[o];
    }
    __syncthreads();
}

__global__ __launch_bounds__(256) void final_merge(
        const double* __restrict__ pvT, const double* __restrict__ pvB,
        const int* __restrict__ piT, const int* __restrict__ piB,
        int* __restrict__ out) {
    __shared__ double Mv[256 * SLOT];   // 22528 B
    __shared__ int    Mi[256 * SLOT];   // 11264 B
    const int q = blockIdx.x;
    merge_query<true >(pvT, piT, q, Mv, Mi, out + q * K);
    merge_query<false>(pvB, piB, q, Mv, Mi, out + NQ * K + q * K);
}

extern "C" void kernel_launch(void* const* d_in, const int* in_sizes, int n_in,
                              void* d_out, int out_size, void* d_ws, size_t ws_size,
                              hipStream_t stream) {
    const float* Q = (const float*)d_in[0];   // [64, 256]
    const float* E = (const float*)d_in[1];   // [10000, 256]
    int* out = (int*)d_out;                   // 640 top idx + 640 bot idx

    // workspace: Se(u32) + strip-major partial lists (7.72 MB, proven size)
    char* ws = (char*)d_ws;
    unsigned* Se  = (unsigned*)(ws);          // 40,960 (padded)
    double*   pvT = (double*)(ws + 40960);    // 500*64*10*8 = 2,560,000
    double*   pvB = (double*)(ws + 2600960);  // 2,560,000
    int*      piT = (int*)   (ws + 5160960);  // 1,280,000
    int*      piB = (int*)   (ws + 6440960);  // 1,280,000

    hipLaunchKernelGGL(ent_sums, dim3(NE / 4), dim3(256), 0, stream, E, Se);
    hipLaunchKernelGGL(jac_part, dim3(NSTRIP * 2), dim3(TPB), LDSBYTES, stream,
                       Q, E, Se, pvT, pvB, piT, piB);
    hipLaunchKernelGGL(final_merge, dim3(NQ), dim3(256), 0, stream,
                       pvT, pvB, piT, piB, out);
}